// Round 3
// baseline (140.478 us; speedup 1.0000x reference)
//
#include <hip/hip_runtime.h>

// Morph2D soft rank-order filter — DIAGNOSTIC BUILD (4x repeated body).
// The body repeats 4x via runtime-opaque offset (zero==0) so the kernel
// exceeds the harness fill dispatches (~44us) and lands in rocprof top-5
// with its own counters. Result stays exact: (4*res)*0.25f == res.

#define BB 32
#define HH 512
#define WW 512

#define CSWAP(a,b) { float lo_ = fminf(v[a], v[b]); float hi_ = fmaxf(v[a], v[b]); v[a] = lo_; v[b] = hi_; }

__global__ __launch_bounds__(256) void morph2d_kernel(
    const float* __restrict__ x, const float* __restrict__ se9,
    const float* __restrict__ rank, float* __restrict__ out,
    int zero, float invR)
{
    int nper = gridDim.x >> 3;
    int lb   = (blockIdx.x & 7) * nper + (blockIdx.x >> 3);
    int g    = lb * 256 + threadIdx.x;

    int gx = g & 127;            // 128 x-groups of 4 px
    int yg = (g >> 7) & 255;     // 256 y-groups of 2 rows
    int b  = g >> 15;
    int x4 = gx << 2;
    int y0 = yg << 1;

    // softmax(rank) + se (uniform across lanes)
    float se[9], w[9];
    {
        float r[9]; float m = -3.4e38f;
        #pragma unroll
        for (int i = 0; i < 9; ++i) { r[i] = rank[i]; m = fmaxf(m, r[i]); }
        float s = 0.f;
        #pragma unroll
        for (int i = 0; i < 9; ++i) { r[i] = __expf(r[i] - m); s += r[i]; }
        float inv = 1.0f / s;
        #pragma unroll
        for (int i = 0; i < 9; ++i) { w[i] = r[i] * inv; se[i] = se9[i]; }
    }

    const float* img0 = x + (size_t)b * (HH * WW);

    float4 acc0 = {0.f, 0.f, 0.f, 0.f};
    float4 acc1 = {0.f, 0.f, 0.f, 0.f};

    #pragma unroll
    for (int it = 0; it < 4; ++it) {
        const float* img = img0 + (size_t)it * zero;   // == img0 at runtime

        float rv[4][6];
        #pragma unroll
        for (int r = 0; r < 4; ++r) {
            int ry  = y0 - 1 + r;
            int ryc = min(max(ry, 0), HH - 1);
            const float* row = img + ryc * WW;
            float4 c  = *(const float4*)(row + x4);
            float  lf = row[max(x4 - 1, 0)];
            float  rt = row[min(x4 + 4, WW - 1)];
            float  m  = (ry >= 0 && ry < HH) ? 1.0f : 0.0f;
            rv[r][0] = ((x4 == 0)      ? 0.f : lf) * m;
            rv[r][1] = c.x * m;
            rv[r][2] = c.y * m;
            rv[r][3] = c.z * m;
            rv[r][4] = c.w * m;
            rv[r][5] = ((x4 + 4 >= WW) ? 0.f : rt) * m;
        }

        #pragma unroll
        for (int r = 0; r < 2; ++r) {
            float4 res;
            float* resp = &res.x;
            #pragma unroll
            for (int j = 0; j < 4; ++j) {
                float v[9];
                #pragma unroll
                for (int dy = 0; dy < 3; ++dy) {
                    v[dy*3+0] = rv[r+dy][j]   * se[dy*3+0];
                    v[dy*3+1] = rv[r+dy][j+1] * se[dy*3+1];
                    v[dy*3+2] = rv[r+dy][j+2] * se[dy*3+2];
                }
                CSWAP(0,3) CSWAP(1,7) CSWAP(2,5) CSWAP(4,8)
                CSWAP(0,7) CSWAP(2,4) CSWAP(3,8) CSWAP(5,6)
                CSWAP(0,2) CSWAP(1,3) CSWAP(4,5) CSWAP(7,8)
                CSWAP(1,4) CSWAP(3,6) CSWAP(5,7)
                CSWAP(0,1) CSWAP(2,4) CSWAP(3,5) CSWAP(6,8)
                CSWAP(2,3) CSWAP(4,5) CSWAP(6,7)
                CSWAP(1,2) CSWAP(3,4) CSWAP(5,6)

                float acc = 0.f;
                #pragma unroll
                for (int i = 0; i < 9; ++i) acc = fmaf(v[i], w[i], acc);
                resp[j] = acc;
            }
            if (r == 0) {
                acc0.x += res.x; acc0.y += res.y; acc0.z += res.z; acc0.w += res.w;
            } else {
                acc1.x += res.x; acc1.y += res.y; acc1.z += res.z; acc1.w += res.w;
            }
        }
    }

    float4 o0 = { acc0.x * invR, acc0.y * invR, acc0.z * invR, acc0.w * invR };
    float4 o1 = { acc1.x * invR, acc1.y * invR, acc1.z * invR, acc1.w * invR };
    *(float4*)(out + (((size_t)b * HH + y0)     * WW + x4)) = o0;
    *(float4*)(out + (((size_t)b * HH + y0 + 1) * WW + x4)) = o1;
}

extern "C" void kernel_launch(void* const* d_in, const int* in_sizes, int n_in,
                              void* d_out, int out_size, void* d_ws, size_t ws_size,
                              hipStream_t stream) {
    const float* x    = (const float*)d_in[0];
    const float* se   = (const float*)d_in[1];
    const float* rank = (const float*)d_in[2];
    float* out = (float*)d_out;

    const int total_threads = BB * (HH / 2) * (WW / 4);   // 1,048,576
    morph2d_kernel<<<total_threads / 256, 256, 0, stream>>>(
        x, se, rank, out, /*zero=*/0, /*invR=*/0.25f);
}

// Round 4
// 96.582 us; speedup vs baseline: 1.4545x; 1.4545x over previous
//
#include <hip/hip_runtime.h>

// Morph2D soft rank-order filter:
//   patches(3x3, zero-pad SAME) * se -> sort ascending -> dot softmax(rank)
// x: [32,512,512,1] fp32 -> out same shape.
//
// R4: latency/occupancy attack. 1 row x 4 px per thread (2M threads,
// 8192 blocks = 32 blocks/CU), se/w scalarized to SGPRs (readfirstlane),
// uniform y-border branch, launch_bounds(256,8) targeting VGPR<=64.

#define HH 512
#define WW 512

#define RFL(x) __int_as_float(__builtin_amdgcn_readfirstlane(__float_as_int(x)))
#define CSWAP(a,b) { float lo_ = fminf(v[a], v[b]); float hi_ = fmaxf(v[a], v[b]); v[a] = lo_; v[b] = hi_; }

__global__ __launch_bounds__(256, 8) void morph2d_kernel(
    const float* __restrict__ x, const float* __restrict__ se9,
    const float* __restrict__ rank, float* __restrict__ out)
{
    // XCD-aware swizzle: contiguous chunk of blocks per XCD
    int nper = gridDim.x >> 3;
    int lb   = (blockIdx.x & 7) * nper + (blockIdx.x >> 3);
    int g    = lb * 256 + threadIdx.x;        // 2,097,152 total, exact

    int gx = g & 127;             // x-group of 4 px
    int y  = (g >> 7) & 511;      // row (wave-uniform)
    int b  = g >> 16;             // batch
    int x4 = gx << 2;

    const float* img = x + (size_t)b * (HH * WW);
    int offL = max(x4 - 1, 0);
    int offR = min(x4 + 4, WW - 1);

    // ---- loads first (wave-uniform y-border branch) ----
    float rv[3][6];
    if (y > 0 && y < HH - 1) {
        const float* p = img + (y - 1) * WW;
        #pragma unroll
        for (int r = 0; r < 3; ++r) {
            float4 c = *(const float4*)(p + x4);
            float lf = p[offL];
            float rt = p[offR];
            rv[r][0] = lf;  rv[r][1] = c.x; rv[r][2] = c.y;
            rv[r][3] = c.z; rv[r][4] = c.w; rv[r][5] = rt;
            p += WW;
        }
    } else {
        #pragma unroll
        for (int r = 0; r < 3; ++r) {
            int ry  = y - 1 + r;
            int ryc = min(max(ry, 0), HH - 1);
            const float* p = img + ryc * WW;
            float  m = (ry >= 0 && ry < HH) ? 1.f : 0.f;
            float4 c = *(const float4*)(p + x4);
            rv[r][0] = p[offL] * m; rv[r][1] = c.x * m; rv[r][2] = c.y * m;
            rv[r][3] = c.z * m;     rv[r][4] = c.w * m; rv[r][5] = p[offR] * m;
        }
    }

    // ---- softmax numerator + se under the load shadow; scalarize ----
    float w[9], se[9];
    float inv_s;
    {
        float s = 0.f;
        float e[9];
        #pragma unroll
        for (int i = 0; i < 9; ++i) { e[i] = __expf(rank[i]); s += e[i]; }
        inv_s = RFL(1.0f / s);
        #pragma unroll
        for (int i = 0; i < 9; ++i) { w[i] = RFL(e[i]); se[i] = RFL(se9[i]); }
    }

    // ---- x-edge zeroing (branchless, 2 cndmask per row) ----
    #pragma unroll
    for (int r = 0; r < 3; ++r) {
        rv[r][0] = (x4 == 0)       ? 0.f : rv[r][0];
        rv[r][5] = (x4 + 4 >= WW)  ? 0.f : rv[r][5];
    }

    // ---- per-pixel: weight, sort (25 CE), dot ----
    float4 res;
    float* resp = &res.x;
    #pragma unroll
    for (int j = 0; j < 4; ++j) {
        float v[9];
        #pragma unroll
        for (int dy = 0; dy < 3; ++dy) {
            v[dy*3+0] = rv[dy][j]   * se[dy*3+0];
            v[dy*3+1] = rv[dy][j+1] * se[dy*3+1];
            v[dy*3+2] = rv[dy][j+2] * se[dy*3+2];
        }
        // optimal 9-input sorting network: 25 CE, depth 7
        CSWAP(0,3) CSWAP(1,7) CSWAP(2,5) CSWAP(4,8)
        CSWAP(0,7) CSWAP(2,4) CSWAP(3,8) CSWAP(5,6)
        CSWAP(0,2) CSWAP(1,3) CSWAP(4,5) CSWAP(7,8)
        CSWAP(1,4) CSWAP(3,6) CSWAP(5,7)
        CSWAP(0,1) CSWAP(2,4) CSWAP(3,5) CSWAP(6,8)
        CSWAP(2,3) CSWAP(4,5) CSWAP(6,7)
        CSWAP(1,2) CSWAP(3,4) CSWAP(5,6)

        float acc = 0.f;
        #pragma unroll
        for (int i = 0; i < 9; ++i) acc = fmaf(v[i], w[i], acc);
        resp[j] = acc * inv_s;
    }

    *(float4*)(out + (((size_t)b * HH + y) * WW + x4)) = res;
}

extern "C" void kernel_launch(void* const* d_in, const int* in_sizes, int n_in,
                              void* d_out, int out_size, void* d_ws, size_t ws_size,
                              hipStream_t stream) {
    const float* x    = (const float*)d_in[0];
    const float* se   = (const float*)d_in[1];
    const float* rank = (const float*)d_in[2];
    float* out = (float*)d_out;

    const int total_threads = 32 * HH * (WW / 4);   // 2,097,152
    morph2d_kernel<<<total_threads / 256, 256, 0, stream>>>(x, se, rank, out);
}

// Round 6
// 96.365 us; speedup vs baseline: 1.4578x; 1.0023x over previous
//
#include <hip/hip_runtime.h>

// Morph2D soft rank-order filter:
//   patches(3x3, zero-pad SAME) * se -> sort ascending -> dot softmax(rank)
// x: [32,512,512,1] fp32 -> out same shape.
//
// R6: 4 rows x 4 cols per thread (16 px), all 6 input rows loaded up-front
// into a static register array (18 loads -> one waitcnt region -> compute).
// Straight-line, fully unrolled, no lambdas/slot-reuse (R5's rotating-buffer
// + (256,8) spill path failed post-timing revalidation). (256,4) = no spills.

#define HH 512
#define WW 512

#define RFL(x) __int_as_float(__builtin_amdgcn_readfirstlane(__float_as_int(x)))
#define CSWAP(a,b) { float lo_ = fminf(v[a], v[b]); float hi_ = fmaxf(v[a], v[b]); v[a] = lo_; v[b] = hi_; }
#define SORT9 \
    CSWAP(0,3) CSWAP(1,7) CSWAP(2,5) CSWAP(4,8) \
    CSWAP(0,7) CSWAP(2,4) CSWAP(3,8) CSWAP(5,6) \
    CSWAP(0,2) CSWAP(1,3) CSWAP(4,5) CSWAP(7,8) \
    CSWAP(1,4) CSWAP(3,6) CSWAP(5,7) \
    CSWAP(0,1) CSWAP(2,4) CSWAP(3,5) CSWAP(6,8) \
    CSWAP(2,3) CSWAP(4,5) CSWAP(6,7) \
    CSWAP(1,2) CSWAP(3,4) CSWAP(5,6)

__global__ __launch_bounds__(256, 4) void morph2d_kernel(
    const float* __restrict__ x, const float* __restrict__ se9,
    const float* __restrict__ rank, float* __restrict__ out)
{
    // XCD-aware swizzle: contiguous chunk of blocks per XCD
    int nper = gridDim.x >> 3;
    int lb   = (blockIdx.x & 7) * nper + (blockIdx.x >> 3);
    int g    = lb * 256 + threadIdx.x;       // 524,288 total, exact

    int gx = g & 127;             // x-group of 4 px
    int rg = (g >> 7) & 127;      // row-group of 4 rows (wave-uniform)
    int b  = g >> 14;             // batch
    int x4 = gx << 2;
    int y0 = rg << 2;

    const float* img = x + (size_t)b * (HH * WW);
    int offL = max(x4 - 1, 0);
    int offR = min(x4 + 4, WW - 1);

    float R[6][6];   // rows y0-1 .. y0+4, cols x4-1 .. x4+4

    // ---- interior rows (always in-bounds): issue loads back-to-back ----
    #pragma unroll
    for (int r = 1; r <= 4; ++r) {
        const float* p = img + (y0 - 1 + r) * WW;
        float4 c = *(const float4*)(p + x4);
        R[r][0] = p[offL]; R[r][1] = c.x; R[r][2] = c.y;
        R[r][3] = c.z;     R[r][4] = c.w; R[r][5] = p[offR];
    }
    // ---- top halo row (zero iff y0 == 0) ----
    {
        int ry = y0 - 1;
        const float* p = img + max(ry, 0) * WW;
        float4 c = *(const float4*)(p + x4);
        float  m = (ry >= 0) ? 1.f : 0.f;
        R[0][0] = p[offL] * m; R[0][1] = c.x * m; R[0][2] = c.y * m;
        R[0][3] = c.z * m;     R[0][4] = c.w * m; R[0][5] = p[offR] * m;
    }
    // ---- bottom halo row (zero iff y0 + 4 == HH) ----
    {
        int ry = y0 + 4;
        const float* p = img + min(ry, HH - 1) * WW;
        float4 c = *(const float4*)(p + x4);
        float  m = (ry < HH) ? 1.f : 0.f;
        R[5][0] = p[offL] * m; R[5][1] = c.x * m; R[5][2] = c.y * m;
        R[5][3] = c.z * m;     R[5][4] = c.w * m; R[5][5] = p[offR] * m;
    }

    // ---- softmax(rank) (1/s folded in) + se, scalarized, under load shadow ----
    float w0,w1,w2,w3,w4,w5,w6,w7,w8;
    float s0,s1,s2,s3,s4,s5,s6,s7,s8;
    {
        float e[9]; float s = 0.f;
        #pragma unroll
        for (int i = 0; i < 9; ++i) { e[i] = __expf(rank[i]); s += e[i]; }
        float inv = 1.0f / s;
        w0=RFL(e[0]*inv); w1=RFL(e[1]*inv); w2=RFL(e[2]*inv);
        w3=RFL(e[3]*inv); w4=RFL(e[4]*inv); w5=RFL(e[5]*inv);
        w6=RFL(e[6]*inv); w7=RFL(e[7]*inv); w8=RFL(e[8]*inv);
        s0=RFL(se9[0]); s1=RFL(se9[1]); s2=RFL(se9[2]); s3=RFL(se9[3]);
        s4=RFL(se9[4]); s5=RFL(se9[5]); s6=RFL(se9[6]); s7=RFL(se9[7]); s8=RFL(se9[8]);
    }

    // ---- x-edge zeroing (branchless cndmask) ----
    bool xl = (x4 == 0);
    bool xr = (x4 + 4 >= WW);
    #pragma unroll
    for (int r = 0; r < 6; ++r) {
        R[r][0] = xl ? 0.f : R[r][0];
        R[r][5] = xr ? 0.f : R[r][5];
    }

    // ---- 16 px: weight by se, sort (25 CE), dot with softmax weights ----
    #pragma unroll
    for (int r = 0; r < 4; ++r) {
        float res[4];
        #pragma unroll
        for (int j = 0; j < 4; ++j) {
            float v[9];
            v[0] = R[r  ][j]*s0; v[1] = R[r  ][j+1]*s1; v[2] = R[r  ][j+2]*s2;
            v[3] = R[r+1][j]*s3; v[4] = R[r+1][j+1]*s4; v[5] = R[r+1][j+2]*s5;
            v[6] = R[r+2][j]*s6; v[7] = R[r+2][j+1]*s7; v[8] = R[r+2][j+2]*s8;
            SORT9
            float d0 = fmaf(v[0], w0, v[1]*w1);
            float d1 = fmaf(v[2], w2, v[3]*w3);
            float d2 = fmaf(v[4], w4, v[5]*w5);
            float d3 = fmaf(v[6], w6, v[7]*w7);
            float d4 = v[8]*w8;
            res[j] = (d0 + d1) + (d2 + d3) + d4;
        }
        float4 o = { res[0], res[1], res[2], res[3] };
        *(float4*)(out + (((size_t)b * HH + (y0 + r)) * WW + x4)) = o;
    }
}

extern "C" void kernel_launch(void* const* d_in, const int* in_sizes, int n_in,
                              void* d_out, int out_size, void* d_ws, size_t ws_size,
                              hipStream_t stream) {
    const float* x    = (const float*)d_in[0];
    const float* se   = (const float*)d_in[1];
    const float* rank = (const float*)d_in[2];
    float* out = (float*)d_out;

    const int total_threads = 32 * (HH / 4) * (WW / 4);   // 524,288
    morph2d_kernel<<<total_threads / 256, 256, 0, stream>>>(x, se, rank, out);
}